// Round 4
// baseline (6440.838 us; speedup 1.0000x reference)
//
#include <hip/hip_runtime.h>
#include <stdint.h>
#include <stddef.h>

// Variational-dropout LSTM, SEQ=256, B=64, IN=H=1024, fp32 I/O.
//
// R4: ONE persistent kernel (cooperative launch, 256 blocks x 256 threads,
// co-residency guaranteed) with a hand-rolled per-step flag barrier —
// eliminates the ~10us/launch kernel-boundary cost that dominated R3.
// Cross-XCD h-exchange goes through the L3 coherence point via agent-scope
// (sc1) atomics; NO L2 flushes anywhere (that's what made cg::grid.sync cost
// 82us/step in R2).
//   - Block bk owns 4 h-cols x 4 gates (gate-interleaved nl=jh*4+g, proven
//     R2/R3). K=2048 (x-projection folded + recurrent) split over 4 waves,
//     f32x4 LDS reduce, shfl_xor gate gather, cell in fp32 registers.
//   - c, bias, mask_h live in registers across all 256 steps.
//   - mh buffers: if ws >= 84MB, 256 per-step buffers -> plain b128 reads
//     (addresses never reused => freshness guaranteed; L2-shared per XCD).
//     Else 2 ping-pong buffers -> agent-scope atomic (sc1) reads (always
//     served at L3; stale L2 copies never consulted).
//   - Barrier: per-(step,block) byte flag stored sc1 after __syncthreads
//     (whose vmcnt(0) drain orders the sc1 data stores first); wave 0 polls
//     64 u32 = 256 flags with __all + s_sleep.

#define SEQ 256

typedef __attribute__((ext_vector_type(8))) __bf16 bf16x8;
typedef __attribute__((ext_vector_type(4))) float  f32x4;
typedef unsigned short u16;
typedef unsigned int   u32;
typedef unsigned long long u64;

__device__ __forceinline__ u16 f2bf(float f) {
  union { float f; unsigned u; } v; v.f = f;
  unsigned r = v.u + 0x7FFFu + ((v.u >> 16) & 1u);   // RNE
  return (u16)(r >> 16);
}
__device__ __forceinline__ float sigm(float x) {
  return __builtin_amdgcn_rcpf(1.f + __expf(-x));
}
__device__ __forceinline__ float tanh_fast(float x) {
  float xc = fminf(15.f, fmaxf(-15.f, x));
  float t = __expf(-2.f * xc);
  return (1.f - t) * __builtin_amdgcn_rcpf(1.f + t);
}
__device__ __forceinline__ float pick4(int idx, float v0, float v1, float v2, float v3) {
  float lo = (idx & 1) ? v1 : v0;
  float hi = (idx & 1) ? v3 : v2;
  return (idx & 2) ? hi : lo;
}
__device__ __forceinline__ bf16x8 frag_sc1(const u16* base, int fidx) {
  const u64* p = (const u64*)base + (size_t)fidx * 2;
  union { u64 q[2]; bf16x8 v; } u;
  u.q[0] = __hip_atomic_load(p,     __ATOMIC_RELAXED, __HIP_MEMORY_SCOPE_AGENT);
  u.q[1] = __hip_atomic_load(p + 1, __ATOMIC_RELAXED, __HIP_MEMORY_SCOPE_AGENT);
  return u.v;
}

// ws layout (bytes):
//  Wihp  @ 0        : [bk 256][kcw 32][l 64][e 8] bf16 = 8388608
//  Whhp  @ 8388608  : 8388608
//  Ap    @ 16777216 : [s 256][m 4][kwg 32][l 64][e 8] bf16 = 33554432
//  flags @ 50331648 : [s 256][bk 256] u8 = 65536
//  mh    @ 50397184 : nbuf x [m 4][kwg 32][l 64][e 8] bf16 (131072 each)
//        nbuf=256 -> end 83951616 ; nbuf=2 -> end 50659328 (proven budget)

__global__ __launch_bounds__(256) void prep_kernel(
    const float* __restrict__ x, const float* __restrict__ h0,
    const float* __restrict__ mask_x, const float* __restrict__ mask_h,
    const float* __restrict__ Wih, const float* __restrict__ Whh,
    u16* __restrict__ Wihp, u16* __restrict__ Whhp, u16* __restrict__ Ap,
    u16* __restrict__ mh0, u32* __restrict__ flags32)
{
  const unsigned idx = blockIdx.x * 256u + threadIdx.x;  // 0 .. 16777215

  // Ap[s][m][kwg][l][e] = bf16( x[s][b][k] * mask_x[b][k] )
  {
    const unsigned e   = idx & 7u;
    const unsigned l   = (idx >> 3) & 63u;
    const unsigned kwg = (idx >> 9) & 31u;
    const unsigned m   = (idx >> 14) & 3u;
    const unsigned s   = idx >> 16;
    const unsigned b   = m * 16u + (l & 15u);
    const unsigned k   = kwg * 32u + (l >> 4) * 8u + e;
    Ap[idx] = f2bf(x[((size_t)s * 64u + b) * 1024u + k] * mask_x[b * 1024u + k]);
  }
  // W swizzles: [bk][kcw][l][e], n = (nl&3)*1024 + bk*4 + (nl>>2)
  if (idx < 4194304u) {
    const unsigned e   = idx & 7u;
    const unsigned l   = (idx >> 3) & 63u;
    const unsigned kcw = (idx >> 9) & 31u;
    const unsigned bk  = idx >> 14;
    const unsigned nl  = l & 15u;
    const unsigned n   = (nl & 3u) * 1024u + bk * 4u + (nl >> 2);
    const unsigned k   = kcw * 32u + (l >> 4) * 8u + e;
    Wihp[idx] = f2bf(Wih[n * 1024u + k]);
    Whhp[idx] = f2bf(Whh[n * 1024u + k]);
  }
  // mh0[m][kwg][l][e] = bf16(h0 * mask_h)
  if (idx < 65536u) {
    const unsigned e   = idx & 7u;
    const unsigned l   = (idx >> 3) & 63u;
    const unsigned kwg = (idx >> 9) & 31u;
    const unsigned m   = idx >> 14;
    const unsigned b   = m * 16u + (l & 15u);
    const unsigned k   = kwg * 32u + (l >> 4) * 8u + e;
    mh0[idx] = f2bf(h0[b * 1024u + k] * mask_h[b * 1024u + k]);
  }
  if (idx < 16384u) flags32[idx] = 0;   // 65536 flag bytes
}

__global__ __launch_bounds__(256) void lstm_persist(
    const u16* __restrict__ Ap, const u16* __restrict__ Wihp,
    const u16* __restrict__ Whhp, u16* __restrict__ mh,
    unsigned char* __restrict__ flags,
    const float* __restrict__ c0, const float* __restrict__ bih,
    const float* __restrict__ bhh, const float* __restrict__ mask_h,
    float* __restrict__ out, int nbuf)
{
  __shared__ f32x4 lds[4][4][64];   // [w][m][l] 16 KB

  const int tid  = threadIdx.x;
  const int w    = tid >> 6;      // K-slice wave; also owns m-tile w in cell
  const int l    = tid & 63;
  const int bk   = blockIdx.x;    // 4 h-cols
  const int nl   = l & 15;
  const int quad = l >> 4;
  const int g_role = nl & 3;
  const int jh   = nl >> 2;
  const int col  = bk * 4 + jh;
  const bool big = (nbuf == 256);

  // persistent per-lane state (valid on g_role==0 lanes, m-tile = w)
  const float bias_reg = bih[g_role * 1024 + col] + bhh[g_role * 1024 + col];
  float c_reg[4], mask_reg[4];
  #pragma unroll
  for (int r = 0; r < 4; ++r) {
    const int b = w * 16 + quad * 4 + r;
    c_reg[r]    = c0[b * 1024 + col];
    mask_reg[r] = mask_h[b * 1024 + col];
  }

  const bf16x8* WI = (const bf16x8*)Wihp;
  const bf16x8* WH = (const bf16x8*)Whhp;
  const bf16x8* ApV = (const bf16x8*)Ap;

  // mh write-address pieces for this lane's column
  const int kwg_c = col >> 5;
  const int lp_c  = ((col >> 3) & 3) * 16;
  const int e_c   = col & 7;

  #pragma unroll 1
  for (int s = 0; s < SEQ; ++s) {
    const u16* mhin = mh + (size_t)(big ? s : (s & 1)) * 65536;

    f32x4 acc[4] = { {0,0,0,0}, {0,0,0,0}, {0,0,0,0}, {0,0,0,0} };

    // recurrent GEMM, K-slice w*256..+256 of 1024
    #pragma unroll 2
    for (int kw = 0; kw < 8; ++kw) {
      bf16x8 b = WH[(bk * 32 + w * 8 + kw) * 64 + l];
      #pragma unroll
      for (int m = 0; m < 4; ++m) {
        const int fidx = (m * 32 + w * 8 + kw) * 64 + l;
        bf16x8 a = big ? ((const bf16x8*)mhin)[fidx] : frag_sc1(mhin, fidx);
        acc[m] = __builtin_amdgcn_mfma_f32_16x16x32_bf16(a, b, acc[m], 0, 0, 0);
      }
    }
    // x-projection folded in (plain loads, read-only data)
    #pragma unroll 2
    for (int kw = 0; kw < 8; ++kw) {
      bf16x8 b = WI[(bk * 32 + w * 8 + kw) * 64 + l];
      #pragma unroll
      for (int m = 0; m < 4; ++m) {
        bf16x8 a = ApV[((s * 4 + m) * 32 + w * 8 + kw) * 64 + l];
        acc[m] = __builtin_amdgcn_mfma_f32_16x16x32_bf16(a, b, acc[m], 0, 0, 0);
      }
    }
    #pragma unroll
    for (int m = 0; m < 4; ++m) lds[w][m][l] = acc[m];
    __syncthreads();

    f32x4 t = lds[0][w][l];
    #pragma unroll
    for (int ww = 1; ww < 4; ++ww) t += lds[ww][w][l];

    u16* mhout = mh + (size_t)(big ? (s + 1) : ((s + 1) & 1)) * 65536;

    #pragma unroll
    for (int r = 0; r < 4; ++r) {
      const int b = w * 16 + quad * 4 + r;
      const float gp = t[r] + bias_reg;
      const float v1 = __shfl_xor(gp, 1, 64);
      const float v2 = __shfl_xor(gp, 2, 64);
      const float v3 = __shfl_xor(gp, 3, 64);
      const float ig = pick4(g_role,     gp, v1, v2, v3);
      const float fg = pick4(g_role ^ 1, gp, v1, v2, v3);
      const float gg = pick4(g_role ^ 2, gp, v1, v2, v3);
      const float og = pick4(g_role ^ 3, gp, v1, v2, v3);
      const float iv = sigm(ig);
      const float fv = sigm(fg);
      const float gv = tanh_fast(gg);
      const float ov = sigm(og);
      const float cn = fv * c_reg[r] + iv * gv;
      const float hn = ov * tanh_fast(cn);
      c_reg[r] = cn;
      if (g_role == 0) {
        out[((size_t)s * 64 + b) * 1024 + col] = hn;
        if (s < SEQ - 1) {
          // mh(s+1) -> device-scope (sc1) store: visible at L3 for all XCDs
          const u16 hv = f2bf(hn * mask_reg[r]);
          u16* p = mhout + ((w * 32 + kwg_c) * 64 + (lp_c + (b & 15))) * 8 + e_c;
          __hip_atomic_store(p, hv, __ATOMIC_RELAXED, __HIP_MEMORY_SCOPE_AGENT);
        } else {
          out[16777216 + b * 1024 + col] = hn;           // h_n
          out[16777216 + 65536 + b * 1024 + col] = cn;   // c_n
        }
      }
    }

    if (s < SEQ - 1) {
      // barrier: data stores drained by the vmcnt(0) before s_barrier
      __syncthreads();
      if (tid == 0)
        __hip_atomic_store(&flags[s * 256 + bk], (unsigned char)1,
                           __ATOMIC_RELAXED, __HIP_MEMORY_SCOPE_AGENT);
      if (w == 0) {
        const u32* f32p = (const u32*)(flags + s * 256) + l;
        for (;;) {
          u32 v = __hip_atomic_load(f32p, __ATOMIC_RELAXED, __HIP_MEMORY_SCOPE_AGENT);
          if (__all(v == 0x01010101u)) break;
          __builtin_amdgcn_s_sleep(2);
        }
      }
      __syncthreads();
    }
  }
}

extern "C" void kernel_launch(void* const* d_in, const int* in_sizes, int n_in,
                              void* d_out, int out_size, void* d_ws, size_t ws_size,
                              hipStream_t stream)
{
  const float* x      = (const float*)d_in[0];
  const float* h0     = (const float*)d_in[1];
  const float* c0     = (const float*)d_in[2];
  const float* mask_x = (const float*)d_in[3];
  const float* mask_h = (const float*)d_in[4];
  const float* Wih    = (const float*)d_in[5];
  const float* Whh    = (const float*)d_in[6];
  const float* bih    = (const float*)d_in[7];
  const float* bhh    = (const float*)d_in[8];
  float* out = (float*)d_out;

  char* ws = (char*)d_ws;
  u16* Wihp = (u16*)(ws + 0);
  u16* Whhp = (u16*)(ws + 8388608);
  u16* Ap   = (u16*)(ws + 16777216);
  unsigned char* flags = (unsigned char*)(ws + 50331648);
  u16* mh   = (u16*)(ws + 50397184);

  const int nbuf = (ws_size >= (size_t)83951616) ? 256 : 2;

  hipLaunchKernelGGL(prep_kernel, dim3(65536), dim3(256), 0, stream,
                     x, h0, mask_x, mask_h, Wih, Whh,
                     Wihp, Whhp, Ap, mh, (u32*)flags);

  const u16* Ap_c = Ap; const u16* Wihp_c = Wihp; const u16* Whhp_c = Whhp;
  int nbuf_v = nbuf;
  void* args[] = { (void*)&Ap_c, (void*)&Wihp_c, (void*)&Whhp_c,
                   (void*)&mh, (void*)&flags,
                   (void*)&c0, (void*)&bih, (void*)&bhh,
                   (void*)&mask_h, (void*)&out, (void*)&nbuf_v };
  hipLaunchCooperativeKernel((const void*)lstm_persist,
                             dim3(256), dim3(256), args, 0, stream);
}